// Round 9
// baseline (215.962 us; speedup 1.0000x reference)
//
#include <hip/hip_runtime.h>
#include <hip/hip_bf16.h>
#include <cstdint>

typedef __bf16 bf16;
typedef __bf16 bf16x2 __attribute__((ext_vector_type(2)));
typedef __bf16 bf16x4 __attribute__((ext_vector_type(4)));
typedef __bf16 bf16x8 __attribute__((ext_vector_type(8)));
typedef float f32x4 __attribute__((ext_vector_type(4)));
typedef float f32x16 __attribute__((ext_vector_type(16)));
typedef unsigned int u32;

#define B_ 2
#define S_ 2048
#define DM 1024
#define H_ 16
#define HD 64

// async global->LDS 16B: lane l's 16 bytes land at ldsbase + l*16.
__device__ __forceinline__ void gload_lds16(const bf16* g, bf16* l) {
  __builtin_amdgcn_global_load_lds((const __attribute__((address_space(1))) void*)g,
                                   (__attribute__((address_space(3))) void*)l,
                                   16, 0, 0);
}

__device__ __forceinline__ u32 cvt_pk_bf16(float lo, float hi) {
  u32 r;
  asm("v_cvt_pk_bf16_f32 %0, %1, %2" : "=v"(r) : "v"(lo), "v"(hi));
  return r;
}

__device__ __forceinline__ bf16x8 cvt8(f32x4 lo, f32x4 hi) {
  bf16x8 o;
#pragma unroll
  for (int j = 0; j < 4; j++) { o[j] = (bf16)lo[j]; o[j + 4] = (bf16)hi[j]; }
  return o;
}

// ---------------------------------------------------------------------------
// Transpose 4 fp32 1024x1024 weights -> bf16 W^T[n][k] in ws.
__global__ __launch_bounds__(256) void transposeW_k(
    const float* __restrict__ w0, const float* __restrict__ w1,
    const float* __restrict__ w2, const float* __restrict__ w3,
    bf16* __restrict__ t0, bf16* __restrict__ t1,
    bf16* __restrict__ t2, bf16* __restrict__ t3) {
  const float* src = (blockIdx.z == 0) ? w0 : (blockIdx.z == 1) ? w1
                     : (blockIdx.z == 2) ? w2 : w3;
  bf16* dst = (blockIdx.z == 0) ? t0 : (blockIdx.z == 1) ? t1
              : (blockIdx.z == 2) ? t2 : t3;
  __shared__ float tile[32][33];
  const int tx = threadIdx.x, ty = threadIdx.y;  // 32 x 8
  const int x0 = blockIdx.x * 32, y0 = blockIdx.y * 32;
#pragma unroll
  for (int r = 0; r < 4; r++)
    tile[ty + r * 8][tx] = src[(size_t)(y0 + ty + r * 8) * DM + x0 + tx];
  __syncthreads();
#pragma unroll
  for (int r = 0; r < 4; r++)
    dst[(size_t)(x0 + ty + r * 8) * DM + y0 + tx] = (bf16)tile[tx][ty + r * 8];
}

// ---------------------------------------------------------------------------
struct GArgs { const void* A; const bf16* Bt; const float* bias; void* C; };
struct GArgs3 { GArgs g[3]; };

// ---------------------------------------------------------------------------
// QKV GEMM: 128(M) x 256(N) tile, BK=64, 512 thr = 8 waves (2M x 4N),
// per-wave 64x64. A read DIRECTLY as f32 (convert fused) via reg-staging +
// in-kernel bf16 convert + swizzled ds_write; B via global_load_lds.
// Triple-buffer rotation with counted s_waitcnt vmcnt(8) lgkmcnt(0).
// WORK MAP (r8 fix): tx = rem&3 -> 4 CONSECUTIVE wgids (same XCD, adjacent
// launch) share one 512KB f32 A-panel (fetched ~once, was 4x = 100MB);
// the 4 B panels of a z-slice total 2MB = L2-resident per XCD.
// T2 chunk-XOR swizzle (0 measured conflicts), T5 setprio,
// LDS-staged bf16 epilogue (ideal 24.6 MB writes, measured).
__global__ __launch_bounds__(512, 1) void gemm128_k(GArgs3 args, int M, int N,
                                                    int K) {
  // 147456 B = 144 KB: A bufs 3x16KB, B bufs 3x32KB.
  __shared__ __align__(16) bf16 SA_[73728];
  bf16* const SB_ = SA_ + 24576;

  // T1 bijective XCD chunk map: nwg=384, XCD k gets 48 consecutive wgids.
  const int nwg = gridDim.x;
  const int id = blockIdx.x;
  const int wgid = (id & 7) * (nwg >> 3) + (id >> 3);
  const int z = wgid >> 7;               // 128 tiles per matrix
  const int rem = wgid & 127;
  const int tx = rem & 3, ty = rem >> 2;  // 4 consecutive share A panel
  const GArgs ga = args.g[z];
  const int m0 = ty * 128, n0 = tx * 256;

  const int tid = threadIdx.x;
  const int lane = tid & 63, w = tid >> 6;
  const int l15 = lane & 15, q = lane >> 4;
  const int wr = w >> 2, wc = w & 3;     // 2M x 4N

  // ---- A: f32 source, pre-swizzled src + per-lane linear ds_write dest.
  //      LDS chunk c holds G[row][ (c&7) ^ (row&7) ] (same map as B).
  const float* gAf[2];
  int dAwr[2];
#pragma unroll
  for (int i = 0; i < 2; i++) {
    const int ci = i * 512 + w * 64 + lane;
    const int row = ci >> 3, sc = (ci & 7) ^ (row & 7);
    gAf[i] = (const float*)ga.A + (size_t)(m0 + row) * K + sc * 8;
    dAwr[i] = ci * 8;   // element offset (16B per chunk)
  }
  // ---- B: bf16 source, global_load_lds (wave-uniform dest base).
  const bf16* gB[4];
  int dB[4];
#pragma unroll
  for (int i = 0; i < 4; i++) {
    const int ci = i * 512 + w * 64 + lane;
    const int row = ci >> 3, sc = (ci & 7) ^ (row & 7);
    gB[i] = ga.Bt + (size_t)(n0 + row) * K + sc * 8;
    dB[i] = (i * 512 + w * 64) * 8;
  }

  // swizzled read chunk offsets: chunk (kk*4+q) ^ (row&7), row&7 == l15&7
  const int cA0 = (q ^ (l15 & 7)) * 8;
  const int cA1 = ((4 + q) ^ (l15 & 7)) * 8;

  f32x4 acc[4][4] = {};
  const int NT = K >> 6;  // 16

  // ---- prologue: A(0),A(1) via regs -> LDS; B(0),B(1) gload; A(2) in regs.
  f32x4 a0l = *(const f32x4*)(gAf[0]);        // A(0)
  f32x4 a0h = *(const f32x4*)(gAf[0] + 4);
  f32x4 a1l = *(const f32x4*)(gAf[1]);
  f32x4 a1h = *(const f32x4*)(gAf[1] + 4);
  f32x4 c0l = *(const f32x4*)(gAf[0] + 64);   // A(1)
  f32x4 c0h = *(const f32x4*)(gAf[0] + 68);
  f32x4 c1l = *(const f32x4*)(gAf[1] + 64);
  f32x4 c1h = *(const f32x4*)(gAf[1] + 68);
#pragma unroll
  for (int i = 0; i < 4; i++) gload_lds16(gB[i], SB_ + dB[i]);            // B0
  f32x4 p0l = *(const f32x4*)(gAf[0] + 128);  // A(2) staged regs
  f32x4 p0h = *(const f32x4*)(gAf[0] + 132);
  f32x4 p1l = *(const f32x4*)(gAf[1] + 128);
  f32x4 p1h = *(const f32x4*)(gAf[1] + 132);
#pragma unroll
  for (int i = 0; i < 4; i++) gload_lds16(gB[i] + 64, SB_ + 16384 + dB[i]); // B1
  // A(0),A(1) -> LDS (compiler inserts the reg-dep waits)
  *(bf16x8*)(SA_ + dAwr[0]) = cvt8(a0l, a0h);
  *(bf16x8*)(SA_ + dAwr[1]) = cvt8(a1l, a1h);
  *(bf16x8*)(SA_ + 8192 + dAwr[0]) = cvt8(c0l, c0h);
  *(bf16x8*)(SA_ + 8192 + dAwr[1]) = cvt8(c1l, c1h);
  // outstanding: B0(4), A2(4), B1(4); vmcnt(8) -> B0 landed. lgkm: ds_writes.
  asm volatile("s_waitcnt vmcnt(8) lgkmcnt(0)" ::: "memory");
  __builtin_amdgcn_s_barrier();

  for (int t = 0; t < NT; ++t) {
    const int rb = t % 3;
    const int w2 = (t + 2) % 3;  // ds_write A(t+2) + gload B(t+2) target
    // 1. ds_write A-regs(t+2); region's A consumed at iter t-1.
    *(bf16x8*)(SA_ + w2 * 8192 + dAwr[0]) = cvt8(p0l, p0h);
    *(bf16x8*)(SA_ + w2 * 8192 + dAwr[1]) = cvt8(p1l, p1h);
    // 2. issue A(t+3) f32 loads (clamped at tail)
    const int ka = ((t + 3 < NT) ? t + 3 : NT - 1) << 6;
    p0l = *(const f32x4*)(gAf[0] + ka); p0h = *(const f32x4*)(gAf[0] + ka + 4);
    p1l = *(const f32x4*)(gAf[1] + ka); p1h = *(const f32x4*)(gAf[1] + ka + 4);
    // 3. issue B(t+2) gloads (clamped)
    const int kb2 = ((t + 2 < NT) ? t + 2 : NT - 1) << 6;
#pragma unroll
    for (int i = 0; i < 4; i++)
      gload_lds16(gB[i] + kb2, SB_ + w2 * 16384 + dB[i]);

    // 4. compute tile t
    const bf16* Ab = SA_ + rb * 8192;
    const bf16* Bb = SB_ + rb * 16384;
    bf16x8 a[4][2], b[4][2];
#pragma unroll
    for (int mt = 0; mt < 4; mt++) {
      const int ro = (wr * 64 + mt * 16 + l15) * 64;
      a[mt][0] = *(const bf16x8*)(Ab + ro + cA0);
      a[mt][1] = *(const bf16x8*)(Ab + ro + cA1);
    }
#pragma unroll
    for (int nt = 0; nt < 4; nt++) {
      const int ro = (wc * 64 + nt * 16 + l15) * 64;
      b[nt][0] = *(const bf16x8*)(Bb + ro + cA0);
      b[nt][1] = *(const bf16x8*)(Bb + ro + cA1);
    }
    __builtin_amdgcn_s_setprio(1);
#pragma unroll
    for (int mt = 0; mt < 4; mt++)
#pragma unroll
      for (int nt = 0; nt < 4; nt++)
#pragma unroll
        for (int kk = 0; kk < 2; kk++)
          acc[mt][nt] = __builtin_amdgcn_mfma_f32_16x16x32_bf16(
              a[mt][kk], b[nt][kk], acc[mt][nt], 0, 0, 0);
    __builtin_amdgcn_s_setprio(0);

    // 5. counted wait: leaves A(t+3)4 + B(t+2)4; B(t+1) (older) drained.
    asm volatile("s_waitcnt vmcnt(8) lgkmcnt(0)" ::: "memory");
    __builtin_amdgcn_s_barrier();
  }

  // ---- drain stray tail prefetches before reusing LDS for the epilogue.
  asm volatile("s_waitcnt vmcnt(0) lgkmcnt(0)" ::: "memory");
  __builtin_amdgcn_s_barrier();

  // ---- epilogue: per-wave 64x64 C-tile via private LDS (stride 68),
  //      coalesced 128B bf16x8 row stores.
  bf16* Ws = SA_ + w * 4352;  // 64*68 elems = 8704 B/wave
#pragma unroll
  for (int nt = 0; nt < 4; nt++) {
    const float bv = ga.bias[n0 + wc * 64 + nt * 16 + l15];
#pragma unroll
    for (int mt = 0; mt < 4; mt++)
#pragma unroll
      for (int r = 0; r < 4; r++)
        Ws[(mt * 16 + q * 4 + r) * 68 + nt * 16 + l15] =
            (bf16)(acc[mt][nt][r] + bv);
  }
#pragma unroll
  for (int p = 0; p < 8; p++) {
    const int lr = p * 8 + (lane >> 3), c0 = (lane & 7) * 8;
    bf16x4 lo = *(const bf16x4*)(Ws + lr * 68 + c0);
    bf16x4 hi = *(const bf16x4*)(Ws + lr * 68 + c0 + 4);
    bf16x8 o;
#pragma unroll
    for (int j = 0; j < 4; j++) { o[j] = lo[j]; o[j + 4] = hi[j]; }
    *(bf16x8*)((bf16*)ga.C + (size_t)(m0 + wr * 64 + lr) * N + n0 + wc * 64 + c0) = o;
  }
}

// ---------------------------------------------------------------------------
// Out-projection GEMM: 128x128 tile -> 256 blocks = exactly 1 block/CU.
// Triple-buffer / counted-vmcnt(4) / chunk-XOR as gemm128_k. f32 C via
// LDS-staged epilogue -> 128B-aligned f32x4 line stores.
__global__ __launch_bounds__(512, 1) void gemmo_k(const bf16* __restrict__ A,
                                                  const bf16* __restrict__ Bt,
                                                  const float* __restrict__ bias,
                                                  float* __restrict__ C,
                                                  int M, int N, int K) {
  // 96 KB: A bufs 3x16KB, B bufs 3x16KB. Epilogue reuse: 8 waves x 9216B.
  __shared__ __align__(16) bf16 SA_[49152];
  bf16* const SB_ = SA_ + 24576;

  const int id = blockIdx.x;                 // nwg = 256
  const int wgid = (id & 7) * 32 + (id >> 3);
  const int tx = wgid & 7, ty = wgid >> 3;   // 8 consecutive share A panel
  const int m0 = ty * 128, n0 = tx * 128;

  const int tid = threadIdx.x;
  const int lane = tid & 63, w = tid >> 6;
  const int l15 = lane & 15, q = lane >> 4;
  const int wr = w >> 2, wc = w & 3;     // 2M x 4N

  const bf16* gA[2];
  const bf16* gB[2];
  int dd[2];
#pragma unroll
  for (int i = 0; i < 2; i++) {
    const int ci = i * 512 + w * 64 + lane;
    const int row = ci >> 3, sc = (ci & 7) ^ (row & 7);
    gA[i] = A + (size_t)(m0 + row) * K + sc * 8;
    gB[i] = Bt + (size_t)(n0 + row) * K + sc * 8;
    dd[i] = ci * 8;
  }

  const int cA0 = (q ^ (l15 & 7)) * 8;
  const int cA1 = ((4 + q) ^ (l15 & 7)) * 8;

  f32x4 acc[4][2] = {};
  const int NT = K >> 6;  // 16

#pragma unroll
  for (int tt = 0; tt < 2; tt++) {
    const int k0 = tt * 64;
    gload_lds16(gA[0] + k0, SA_ + tt * 8192 + dd[0]);
    gload_lds16(gA[1] + k0, SA_ + tt * 8192 + dd[1]);
    gload_lds16(gB[0] + k0, SB_ + tt * 8192 + dd[0]);
    gload_lds16(gB[1] + k0, SB_ + tt * 8192 + dd[1]);
  }
  asm volatile("s_waitcnt vmcnt(4)" ::: "memory");
  __builtin_amdgcn_s_barrier();

  for (int t = 0; t < NT; ++t) {
    const int rb = t % 3;
    const int wb = (t + 2) % 3;
    const int kpre = ((t + 2 < NT) ? t + 2 : NT - 1) << 6;
    gload_lds16(gA[0] + kpre, SA_ + wb * 8192 + dd[0]);
    gload_lds16(gA[1] + kpre, SA_ + wb * 8192 + dd[1]);
    gload_lds16(gB[0] + kpre, SB_ + wb * 8192 + dd[0]);
    gload_lds16(gB[1] + kpre, SB_ + wb * 8192 + dd[1]);

    const bf16* Ab = SA_ + rb * 8192;
    const bf16* Bb = SB_ + rb * 8192;
    bf16x8 a[4][2], b[2][2];
#pragma unroll
    for (int mt = 0; mt < 4; mt++) {
      const int ro = (wr * 64 + mt * 16 + l15) * 64;
      a[mt][0] = *(const bf16x8*)(Ab + ro + cA0);
      a[mt][1] = *(const bf16x8*)(Ab + ro + cA1);
    }
#pragma unroll
    for (int nt = 0; nt < 2; nt++) {
      const int ro = (wc * 32 + nt * 16 + l15) * 64;
      b[nt][0] = *(const bf16x8*)(Bb + ro + cA0);
      b[nt][1] = *(const bf16x8*)(Bb + ro + cA1);
    }

    __builtin_amdgcn_s_setprio(1);
#pragma unroll
    for (int mt = 0; mt < 4; mt++)
#pragma unroll
      for (int nt = 0; nt < 2; nt++)
#pragma unroll
        for (int kk = 0; kk < 2; kk++)
          acc[mt][nt] = __builtin_amdgcn_mfma_f32_16x16x32_bf16(
              a[mt][kk], b[nt][kk], acc[mt][nt], 0, 0, 0);
    __builtin_amdgcn_s_setprio(0);

    asm volatile("s_waitcnt vmcnt(4)" ::: "memory");
    __builtin_amdgcn_s_barrier();
  }

  // ---- drain tail prefetches before LDS reuse.
  asm volatile("s_waitcnt vmcnt(0)" ::: "memory");
  __builtin_amdgcn_s_barrier();

  // ---- epilogue: per-wave 64x32 f32 tile via LDS (stride 36 f32),
  //      then 128B f32x4 line stores.
  float* Ws = (float*)SA_ + w * 2304;  // 64*36 f32 = 9216 B/wave
#pragma unroll
  for (int nt = 0; nt < 2; nt++) {
    const float bv = bias[n0 + wc * 32 + nt * 16 + l15];
#pragma unroll
    for (int mt = 0; mt < 4; mt++)
#pragma unroll
      for (int r = 0; r < 4; r++)
        Ws[(mt * 16 + q * 4 + r) * 36 + nt * 16 + l15] = acc[mt][nt][r] + bv;
  }
#pragma unroll
  for (int p = 0; p < 8; p++) {
    const int lr = p * 8 + (lane >> 3), c0 = (lane & 7) * 4;
    f32x4 v = *(const f32x4*)(Ws + lr * 36 + c0);
    *(f32x4*)(C + (size_t)(m0 + wr * 64 + lr) * N + n0 + wc * 32 + c0) = v;
  }
}

// ---------------------------------------------------------------------------
// Causal flash attention (round-7 measured-good). 32x32x16 MFMA, swapped
// QK^T (S^T = K@Q^T), P in registers (cvt_pk_bf16 + permlane32_swap).
// 128-row Q tile per block, 512 threads = 8 waves = (q-quarter qq) x
// (key-half kh). Grid 512 = 2 blocks/CU co-resident (16 waves/CU); paired
// xt = tau<8 ? tau : 23-tau -> uniform 34 iters per CU.
__global__ __launch_bounds__(512, 4) void attn_k(const bf16* __restrict__ Qp,
                                                 const bf16* __restrict__ Kp,
                                                 const bf16* __restrict__ Vp,
                                                 bf16* __restrict__ Op) {
  const int g = blockIdx.x;          // 0..511
  const int xcd = g & 7, s = g >> 3;
  const int gl = s & 3, tau = s >> 2;        // (b,h)-in-XCD, tile slot 0..15
  const int bh = xcd * 4 + gl;
  const int b = bh >> 4, h = bh & 15;
  const int xt = (tau < 8) ? tau : 23 - tau;  // pair {t,t+8}: xt sums to 15
  const int i0 = xt * 128;
  const int NI = 2 * xt + 2;                  // 64-key tiles, >= 2

  const int tid = threadIdx.x;
  const int lane = tid & 63, w = tid >> 6;
  const int l31 = lane & 31, hi = lane >> 5;
  const int qq = w >> 1, kh = w & 1;          // q-quarter, key-half

  // staging 32KB ([2][64][64] x2); epilogue reuse 32KB osum + 1KB aux
  __shared__ __align__(16) char smem[33792];
  bf16 (*Ks)[64][64] = (bf16 (*)[64][64])smem;             // [2][64][64] swz
  bf16 (*Vts)[64][64] = (bf16 (*)[64][64])(smem + 16384);  // [2][64][64] [d][k]

  const size_t headoff = (size_t)b * S_ * DM + h * HD;
  const bf16* Kb = Kp + headoff;
  const bf16* Vb = Vp + headoff;

  // K staging: 512 threads x one bf16x8 = 64x64.
  const int kr = tid >> 3, kcb = (tid & 7) * 8;
  const int cK = ((tid & 7) ^ (kr & 7)) * 8;
  // V staging: 4 keys x 2 d per thread.
  const int d0 = (tid & 31) * 2, kq = (tid >> 5) * 4;
  const int cV0 = ((kq >> 3) ^ (d0 & 7)) * 8 + (kq & 7);
  const int cV1 = ((kq >> 3) ^ ((d0 + 1) & 7)) * 8 + (kq & 7);
  const float QSCALE = 0.04508422f;  // log2(e)/32

  // ---- Q -> registers in B-frag layout (n=q=l31, k=kk*16+hi*8+j), prescaled
  bf16x8 qreg[4];
  {
    const bf16* qb = Qp + headoff + (size_t)(i0 + qq * 32 + l31) * DM + hi * 8;
#pragma unroll
    for (int kk = 0; kk < 4; kk++) {
      bf16x8 v = *(const bf16x8*)(qb + kk * 16);
      bf16x8 o;
#pragma unroll
      for (int j = 0; j < 8; j++) o[j] = (bf16)((float)v[j] * QSCALE);
      qreg[kk] = o;
    }
  }

  // ---- prologue: tile 0 -> buf 0; issue tile 1 into regs (NI >= 2 always)
  bf16x8 kR = *(const bf16x8*)(Kb + (size_t)kr * DM + kcb);
  bf16x2 vR[4];
#pragma unroll
  for (int j = 0; j < 4; j++)
    vR[j] = *(const bf16x2*)(Vb + (size_t)(kq + j) * DM + d0);
  *(bf16x8*)&Ks[0][kr][cK] = kR;
  {
    bf16x4 vlo, vhi;
#pragma unroll
    for (int j = 0; j < 4; j++) { vlo[j] = vR[j][0]; vhi[j] = vR[j][1]; }
    *(bf16x4*)&Vts[0][d0][cV0] = vlo;
    *(bf16x4*)&Vts[0][d0 + 1][cV1] = vhi;
  }
  kR = *(const bf16x8*)(Kb + (size_t)(64 + kr) * DM + kcb);
#pragma unroll
  for (int j = 0; j < 4; j++)
    vR[j] = *(const bf16x2*)(Vb + (size_t)(64 + kq + j) * DM + d0);
  __syncthreads();

  f32x16 oacc0 = {}, oacc1 = {};  // O^T partial: d-tiles 0..31 / 32..63, col q
  float rsum = 0.f;
  int buf = 0;
  const int qbase = i0 + qq * 32;

  for (int t = 0; t < NI; ++t, buf ^= 1) {
    // ---- write tile t+1 (regs loaded at t-1; latency budget = full iter)
    if (t + 1 < NI) {
      *(bf16x8*)&Ks[buf ^ 1][kr][cK] = kR;
      bf16x4 vlo, vhi;
#pragma unroll
      for (int j = 0; j < 4; j++) { vlo[j] = vR[j][0]; vhi[j] = vR[j][1]; }
      *(bf16x4*)&Vts[buf ^ 1][d0][cV0] = vlo;
      *(bf16x4*)&Vts[buf ^ 1][d0 + 1][cV1] = vhi;
    }
    // ---- issue loads for tile t+2
    if (t + 2 < NI) {
      const size_t jn = (size_t)(t + 2) * 64;
      kR = *(const bf16x8*)(Kb + (jn + kr) * DM + kcb);
#pragma unroll
      for (int j = 0; j < 4; j++)
        vR[j] = *(const bf16x2*)(Vb + (jn + kq + j) * DM + d0);
    }

    const int kbase = t * 64 + kh * 32;
    if (kbase <= qbase + 31) {  // not fully masked for this wave
      // ---- S^T = K @ Q^T, 2+2 split accumulator chains
      f32x16 sa = {}, sb = {};
      __builtin_amdgcn_s_setprio(1);
#pragma unroll
      for (int kk = 0; kk < 2; kk++) {
        bf16x8 ka = *(const bf16x8*)
            &Ks[buf][kh * 32 + l31][((2 * kk + hi) ^ (l31 & 7)) * 8];
        sa = __builtin_amdgcn_mfma_f32_32x32x16_bf16(ka, qreg[kk], sa, 0, 0, 0);
      }
#pragma unroll
      for (int kk = 2; kk < 4; kk++) {
        bf16x8 ka = *(const bf16x8*)
            &Ks[buf][kh * 32 + l31][((2 * kk + hi) ^ (l31 & 7)) * 8];
        sb = __builtin_amdgcn_mfma_f32_32x32x16_bf16(ka, qreg[kk], sb, 0, 0, 0);
      }
      __builtin_amdgcn_s_setprio(0);

      // ---- p = exp2(sa+sb). C-layout: col=q=l31, row=key=(r&3)+8*(r>>2)+4*hi
      float p[16];
      if (kbase + 31 > qbase) {  // diagonal-crossing: predicated
        const int qrl = qbase + l31;
#pragma unroll
        for (int r = 0; r < 16; r++) {
          const int keyl = kbase + (r & 3) + 8 * (r >> 2) + 4 * hi;
          p[r] = (keyl <= qrl) ? __builtin_amdgcn_exp2f(sa[r] + sb[r]) : 0.f;
        }
      } else {
#pragma unroll
        for (int r = 0; r < 16; r++)
          p[r] = __builtin_amdgcn_exp2f(sa[r] + sb[r]);
      }
      // tree-reduce rsum
      {
        float q0 = (p[0] + p[1]) + (p[2] + p[3]);
        float q1 = (p[4] + p[5]) + (p[6] + p[7]);
        float q2 = (p[8] + p[9]) + (p[10] + p[11]);
        float q3 = (p[12] + p[13]) + (p[14] + p[15]);
        rsum += (q0 + q1) + (q2 + q3);
      }

      // ---- pack quads to bf16 words
      u32 Aq[4][2];
#pragma unroll
      for (int t2 = 0; t2 < 4; t2++) {
        Aq[t2][0] = cvt_pk_bf16(p[4 * t2 + 0], p[4 * t2 + 1]);
        Aq[t2][1] = cvt_pk_bf16(p[4 * t2 + 2], p[4 * t2 + 3]);
      }
      // ---- exchange to PV B-frag via permlane32_swap
      bf16x8 pb[2];
#pragma unroll
      for (int s2 = 0; s2 < 2; s2++) {
        auto e0 = __builtin_amdgcn_permlane32_swap(Aq[2 * s2][0], Aq[2 * s2 + 1][0], false, false);
        auto e1 = __builtin_amdgcn_permlane32_swap(Aq[2 * s2][1], Aq[2 * s2 + 1][1], false, false);
        union { u32 u[4]; bf16x8 v; } cv;
        cv.u[0] = e0[0]; cv.u[1] = e1[0]; cv.u[2] = e0[1]; cv.u[3] = e1[1];
        pb[s2] = cv.v;
      }

      // ---- O^T += V^T @ P : A = Vts[d][key], B = pb (keys of this kh-half)
      __builtin_amdgcn_s_setprio(1);
#pragma unroll
      for (int s2 = 0; s2 < 2; s2++) {
        const int cv = ((kh * 4 + s2 * 2 + hi) ^ (l31 & 7)) * 8;
        bf16x8 va0 = *(const bf16x8*)&Vts[buf][l31][cv];
        bf16x8 va1 = *(const bf16x8*)&Vts[buf][32 + l31][cv];
        oacc0 = __builtin_amdgcn_mfma_f32_32x32x16_bf16(va0, pb[s2], oacc0, 0, 0, 0);
        oacc1 = __builtin_amdgcn_mfma_f32_32x32x16_bf16(va1, pb[s2], oacc1, 0, 0, 0);
      }
      __builtin_amdgcn_s_setprio(0);
    }

    __syncthreads();  // tile t reads done + tile t+1 writes visible
  }

  // ---- cross-wave (kh) reduction + transposed coalesced output ----
  // osum [qq][slot=8][lane=64][4] f32 (32 KB): kh=0 waves write, kh=1 add.
  float rtot_w = rsum + __shfl_xor(rsum, 32);
  float* osum = (float*)smem;
  float* auxf = (float*)(smem + 32768);   // [w][32] rsum partials
  if (kh == 0) {
#pragma unroll
    for (int m = 0; m < 2; m++)
#pragma unroll
      for (int rq = 0; rq < 4; rq++) {
        f32x4 v4;
#pragma unroll
        for (int e = 0; e < 4; e++)
          v4[e] = m ? oacc1[rq * 4 + e] : oacc0[rq * 4 + e];
        *(f32x4*)(osum + qq * 2048 + (m * 4 + rq) * 256 + lane * 4) = v4;
      }
  }
  if (lane < 32) auxf[w * 32 + lane] = rtot_w;
  __syncthreads();
  if (kh == 1) {
#pragma unroll
    for (int m = 0; m < 2; m++)
#pragma unroll
      for (int rq = 0; rq < 4; rq++) {
        float* pp = osum + qq * 2048 + (m * 4 + rq) * 256 + lane * 4;
        f32x4 v4 = *(f32x4*)pp;
#pragma unroll
        for (int e = 0; e < 4; e++)
          v4[e] += m ? oacc1[rq * 4 + e] : oacc0[rq * 4 + e];
        *(f32x4*)pp = v4;
      }
  }
  __syncthreads();

  {
    const int q = tid >> 2, q31b = q & 31, qq2 = q >> 5;
    const float rtot = auxf[(qq2 * 2 + 0) * 32 + q31b] + auxf[(qq2 * 2 + 1) * 32 + q31b];
    const float rinv = 1.0f / rtot;
    const int dbase = (tid & 3) * 16;
    bf16* orow = Op + headoff + (size_t)(i0 + q) * DM + dbase;
#pragma unroll
    for (int gg = 0; gg < 2; gg++) {
      bf16x8 o8;
#pragma unroll
      for (int e = 0; e < 8; e++) {
        const int d = dbase + gg * 8 + e;
        const int base = (((d >> 5) << 2) | ((d >> 3) & 3)) * 256 +
                         (q31b + 32 * ((d >> 2) & 1)) * 4 + (d & 3);
        o8[e] = (bf16)(osum[qq2 * 2048 + base] * rinv);
      }
      *(bf16x8*)(orow + gg * 8) = o8;
    }
  }
}

// ---------------------------------------------------------------------------
extern "C" void kernel_launch(void* const* d_in, const int* in_sizes, int n_in,
                              void* d_out, int out_size, void* d_ws, size_t ws_size,
                              hipStream_t stream) {
  const float* q_in = (const float*)d_in[0];
  const float* k_in = (const float*)d_in[1];
  const float* v_in = (const float*)d_in[2];
  // d_in[3] = causal mask, implemented analytically
  const float* Wq = (const float*)d_in[4];
  const float* bq = (const float*)d_in[5];
  const float* Wk = (const float*)d_in[6];
  const float* bk = (const float*)d_in[7];
  const float* Wv = (const float*)d_in[8];
  const float* bv = (const float*)d_in[9];
  const float* Wo = (const float*)d_in[10];
  const float* bo = (const float*)d_in[11];

  bf16* ws = (bf16*)d_ws;
  const size_t NQ = (size_t)B_ * S_ * DM;  // 4M elements
  bf16* Qp = ws;                           // attn writes in-place
  bf16* Kp = ws + NQ;
  bf16* Vp = ws + 2 * NQ;
  bf16* WqT = ws + 3 * NQ;                 // bf16 W^T, 1M elems each
  bf16* WkT = WqT + (size_t)DM * DM;
  bf16* WvT = WkT + (size_t)DM * DM;
  bf16* WoT = WvT + (size_t)DM * DM;       // 32 MB total

  transposeW_k<<<dim3(32, 32, 4), dim3(32, 8), 0, stream>>>(
      Wq, Wk, Wv, Wo, WqT, WkT, WvT, WoT);

  // QKV: reads f32 activations directly (convert fused into A-staging)
  GArgs3 g3;
  g3.g[0] = {q_in, WqT, bq, Qp};
  g3.g[1] = {k_in, WkT, bk, Kp};
  g3.g[2] = {v_in, WvT, bv, Vp};
  gemm128_k<<<dim3(384), 512, 0, stream>>>(g3, B_ * S_, DM, DM);

  // 128-row Q tiles: 16 tiles x 32 (b,h) = 512 blocks x 512 threads
  attn_k<<<dim3(512, 1, 1), 512, 0, stream>>>(Qp, Kp, Vp, Qp);

  // out-projection: 128x128 tiles -> 256 blocks = exactly 1 block/CU
  gemmo_k<<<dim3(256), 512, 0, stream>>>(Qp, WoT, bo, (float*)d_out,
                                         B_ * S_, DM, DM);
}

// Round 11
// 210.500 us; speedup vs baseline: 1.0259x; 1.0259x over previous
//
#include <hip/hip_runtime.h>
#include <hip/hip_bf16.h>
#include <cstdint>

typedef __bf16 bf16;
typedef __bf16 bf16x2 __attribute__((ext_vector_type(2)));
typedef __bf16 bf16x4 __attribute__((ext_vector_type(4)));
typedef __bf16 bf16x8 __attribute__((ext_vector_type(8)));
typedef float f32x4 __attribute__((ext_vector_type(4)));
typedef float f32x16 __attribute__((ext_vector_type(16)));
typedef unsigned int u32;

#define B_ 2
#define S_ 2048
#define DM 1024
#define H_ 16
#define HD 64

// async global->LDS 16B: lane l's 16 bytes land at ldsbase + l*16.
__device__ __forceinline__ void gload_lds16(const bf16* g, bf16* l) {
  __builtin_amdgcn_global_load_lds((const __attribute__((address_space(1))) void*)g,
                                   (__attribute__((address_space(3))) void*)l,
                                   16, 0, 0);
}

__device__ __forceinline__ u32 cvt_pk_bf16(float lo, float hi) {
  u32 r;
  asm("v_cvt_pk_bf16_f32 %0, %1, %2" : "=v"(r) : "v"(lo), "v"(hi));
  return r;
}

__device__ __forceinline__ bf16x8 cvt8(f32x4 lo, f32x4 hi) {
  bf16x8 o;
#pragma unroll
  for (int j = 0; j < 4; j++) { o[j] = (bf16)lo[j]; o[j + 4] = (bf16)hi[j]; }
  return o;
}

// ---------------------------------------------------------------------------
// Transpose 4 fp32 1024x1024 weights -> bf16 W^T[n][k] in ws.
__global__ __launch_bounds__(256) void transposeW_k(
    const float* __restrict__ w0, const float* __restrict__ w1,
    const float* __restrict__ w2, const float* __restrict__ w3,
    bf16* __restrict__ t0, bf16* __restrict__ t1,
    bf16* __restrict__ t2, bf16* __restrict__ t3) {
  const float* src = (blockIdx.z == 0) ? w0 : (blockIdx.z == 1) ? w1
                     : (blockIdx.z == 2) ? w2 : w3;
  bf16* dst = (blockIdx.z == 0) ? t0 : (blockIdx.z == 1) ? t1
              : (blockIdx.z == 2) ? t2 : t3;
  __shared__ float tile[32][33];
  const int tx = threadIdx.x, ty = threadIdx.y;  // 32 x 8
  const int x0 = blockIdx.x * 32, y0 = blockIdx.y * 32;
#pragma unroll
  for (int r = 0; r < 4; r++)
    tile[ty + r * 8][tx] = src[(size_t)(y0 + ty + r * 8) * DM + x0 + tx];
  __syncthreads();
#pragma unroll
  for (int r = 0; r < 4; r++)
    dst[(size_t)(x0 + ty + r * 8) * DM + y0 + tx] = (bf16)tile[tx][ty + r * 8];
}

// ---------------------------------------------------------------------------
struct GArgs { const void* A; const bf16* Bt; const float* bias; void* C; };
struct GArgs3 { GArgs g[3]; };

// ---------------------------------------------------------------------------
// QKV GEMM: 128(M) x 256(N) tile, BK=64, 512 thr = 8 waves (2M x 4N),
// per-wave 64x64. A read DIRECTLY as f32 (convert fused) via 2-SET
// reg-staging + post-MFMA ds_write (r9 fix: the r8 head-of-iteration
// ds_write forced an implicit vmcnt(4) stall at the barrier with zero
// compute cover -> +14us; now the A-write sits AFTER the MFMA cluster and
// its regs were loaded TWO iterations earlier). B via global_load_lds.
// Iter t: {gload B(t+2); MFMA(t); ds_write A(t+2) [loaded t-2]; load
// A(t+4) into the written set; s_waitcnt vmcnt(12) lgkmcnt(0); barrier}.
// vmcnt(12) leaves exactly {A(t+3),B(t+2),A(t+4)}; drains B(t+1),A(t+2).
// Parity-unrolled x2 so the 2 A-reg sets are statically indexed (rule 20).
// Work map = r8 (consecutive wgids share B panel; A-sharing map was
// falsified in r9: -60MB fetch but +4us, kernel is stall- not BW-bound).
// T2 chunk-XOR swizzle (0 measured conflicts), T5 setprio,
// LDS-staged bf16 epilogue (ideal 24.6 MB writes, measured).
__global__ __launch_bounds__(512, 1) void gemm128_k(GArgs3 args, int M, int N,
                                                    int K) {
  // 147456 B = 144 KB: A bufs 3x16KB, B bufs 3x32KB.
  __shared__ __align__(16) bf16 SA_[73728];
  bf16* const SB_ = SA_ + 24576;

  // T1 bijective XCD chunk map: nwg=384, XCD k gets 48 consecutive wgids.
  const int nwg = gridDim.x;
  const int id = blockIdx.x;
  const int wgid = (id & 7) * (nwg >> 3) + (id >> 3);
  const int z = wgid >> 7;               // 128 tiles per matrix
  const int rem = wgid & 127;
  const int tx = rem >> 5, ty = rem & 31;  // consecutive wgids share B panel
  const GArgs ga = args.g[z];
  const int m0 = ty * 128, n0 = tx * 256;

  const int tid = threadIdx.x;
  const int lane = tid & 63, w = tid >> 6;
  const int l15 = lane & 15, q = lane >> 4;
  const int wr = w >> 2, wc = w & 3;     // 2M x 4N

  // ---- A: f32 source, pre-swizzled src + per-lane linear ds_write dest.
  //      LDS chunk c holds G[row][ (c&7) ^ (row&7) ] (same map as B).
  const float* gAf[2];
  int dAwr[2];
#pragma unroll
  for (int i = 0; i < 2; i++) {
    const int ci = i * 512 + w * 64 + lane;
    const int row = ci >> 3, sc = (ci & 7) ^ (row & 7);
    gAf[i] = (const float*)ga.A + (size_t)(m0 + row) * K + sc * 8;
    dAwr[i] = ci * 8;   // element offset (16B per chunk)
  }
  // ---- B: bf16 source, global_load_lds (wave-uniform dest base).
  const bf16* gB[4];
  int dB[4];
#pragma unroll
  for (int i = 0; i < 4; i++) {
    const int ci = i * 512 + w * 64 + lane;
    const int row = ci >> 3, sc = (ci & 7) ^ (row & 7);
    gB[i] = ga.Bt + (size_t)(n0 + row) * K + sc * 8;
    dB[i] = (i * 512 + w * 64) * 8;
  }

  // swizzled read chunk offsets: chunk (kk*4+q) ^ (row&7), row&7 == l15&7
  const int cA0 = (q ^ (l15 & 7)) * 8;
  const int cA1 = ((4 + q) ^ (l15 & 7)) * 8;

  f32x4 acc[4][4] = {};
  const int NT = K >> 6;  // 16

  // ---- prologue: A(0),A(1) -> temps; B(0),B(1) gload; A(2)->set0,
  //      A(3)->set1; ds_write A(0),A(1); counted wait.
  f32x4 a0l = *(const f32x4*)(gAf[0]);        // A(0)
  f32x4 a0h = *(const f32x4*)(gAf[0] + 4);
  f32x4 a1l = *(const f32x4*)(gAf[1]);
  f32x4 a1h = *(const f32x4*)(gAf[1] + 4);
  f32x4 c0l = *(const f32x4*)(gAf[0] + 64);   // A(1)
  f32x4 c0h = *(const f32x4*)(gAf[0] + 68);
  f32x4 c1l = *(const f32x4*)(gAf[1] + 64);
  f32x4 c1h = *(const f32x4*)(gAf[1] + 68);
#pragma unroll
  for (int i = 0; i < 4; i++) gload_lds16(gB[i], SB_ + dB[i]);            // B0
  f32x4 A0_0l = *(const f32x4*)(gAf[0] + 128);  // set0 = A(2)
  f32x4 A0_0h = *(const f32x4*)(gAf[0] + 132);
  f32x4 A0_1l = *(const f32x4*)(gAf[1] + 128);
  f32x4 A0_1h = *(const f32x4*)(gAf[1] + 132);
#pragma unroll
  for (int i = 0; i < 4; i++) gload_lds16(gB[i] + 64, SB_ + 16384 + dB[i]); // B1
  f32x4 A1_0l = *(const f32x4*)(gAf[0] + 192);  // set1 = A(3)
  f32x4 A1_0h = *(const f32x4*)(gAf[0] + 196);
  f32x4 A1_1l = *(const f32x4*)(gAf[1] + 192);
  f32x4 A1_1h = *(const f32x4*)(gAf[1] + 196);
  // A(0),A(1) -> LDS (compiler inserts the reg-dep waits)
  *(bf16x8*)(SA_ + dAwr[0]) = cvt8(a0l, a0h);
  *(bf16x8*)(SA_ + dAwr[1]) = cvt8(a1l, a1h);
  *(bf16x8*)(SA_ + 8192 + dAwr[0]) = cvt8(c0l, c0h);
  *(bf16x8*)(SA_ + 8192 + dAwr[1]) = cvt8(c1l, c1h);
  // outstanding: B0(4), A2(4), B1(4), A3(4); vmcnt(12) -> B0 landed.
  asm volatile("s_waitcnt vmcnt(12) lgkmcnt(0)" ::: "memory");
  __builtin_amdgcn_s_barrier();

  for (int tt = 0; tt < NT; tt += 2) {
#pragma unroll
    for (int half = 0; half < 2; half++) {
      const int t = tt + half;
      const int rb = t % 3;
      const int w2 = (t + 2) % 3;
      // 1. issue B(t+2) gloads (clamped tail keeps accounting uniform)
      const int kb2 = ((t + 2 < NT) ? t + 2 : NT - 1) << 6;
#pragma unroll
      for (int i = 0; i < 4; i++)
        gload_lds16(gB[i] + kb2, SB_ + w2 * 16384 + dB[i]);

      // 2. compute tile t
      const bf16* Ab = SA_ + rb * 8192;
      const bf16* Bb = SB_ + rb * 16384;
      bf16x8 a[4][2], b[4][2];
#pragma unroll
      for (int mt = 0; mt < 4; mt++) {
        const int ro = (wr * 64 + mt * 16 + l15) * 64;
        a[mt][0] = *(const bf16x8*)(Ab + ro + cA0);
        a[mt][1] = *(const bf16x8*)(Ab + ro + cA1);
      }
#pragma unroll
      for (int nt = 0; nt < 4; nt++) {
        const int ro = (wc * 64 + nt * 16 + l15) * 64;
        b[nt][0] = *(const bf16x8*)(Bb + ro + cA0);
        b[nt][1] = *(const bf16x8*)(Bb + ro + cA1);
      }
      __builtin_amdgcn_s_setprio(1);
#pragma unroll
      for (int mt = 0; mt < 4; mt++)
#pragma unroll
        for (int nt = 0; nt < 4; nt++)
#pragma unroll
          for (int kk = 0; kk < 2; kk++)
            acc[mt][nt] = __builtin_amdgcn_mfma_f32_16x16x32_bf16(
                a[mt][kk], b[nt][kk], acc[mt][nt], 0, 0, 0);
      __builtin_amdgcn_s_setprio(0);

      // 3. ds_write A(t+2) (regs loaded at t-2: 2 iters of latency budget;
      //    implicit vmcnt wait sits post-MFMA, count-satisfied) and
      // 4. reload the SAME set with A(t+4) (clamped).
      const int ka = ((t + 4 < NT) ? t + 4 : NT - 1) << 6;
      if (half == 0) {
        *(bf16x8*)(SA_ + w2 * 8192 + dAwr[0]) = cvt8(A0_0l, A0_0h);
        *(bf16x8*)(SA_ + w2 * 8192 + dAwr[1]) = cvt8(A0_1l, A0_1h);
        A0_0l = *(const f32x4*)(gAf[0] + ka);
        A0_0h = *(const f32x4*)(gAf[0] + ka + 4);
        A0_1l = *(const f32x4*)(gAf[1] + ka);
        A0_1h = *(const f32x4*)(gAf[1] + ka + 4);
      } else {
        *(bf16x8*)(SA_ + w2 * 8192 + dAwr[0]) = cvt8(A1_0l, A1_0h);
        *(bf16x8*)(SA_ + w2 * 8192 + dAwr[1]) = cvt8(A1_1l, A1_1h);
        A1_0l = *(const f32x4*)(gAf[0] + ka);
        A1_0h = *(const f32x4*)(gAf[0] + ka + 4);
        A1_1l = *(const f32x4*)(gAf[1] + ka);
        A1_1h = *(const f32x4*)(gAf[1] + ka + 4);
      }

      // 5. counted wait: leaves {A(t+3), B(t+2), A(t+4)} = 12 in flight;
      //    drains B(t+1) (2 iters old) + A(t+2). Never vmcnt(0) in loop.
      asm volatile("s_waitcnt vmcnt(12) lgkmcnt(0)" ::: "memory");
      __builtin_amdgcn_s_barrier();
    }
  }

  // ---- drain stray tail prefetches before reusing LDS for the epilogue.
  asm volatile("s_waitcnt vmcnt(0) lgkmcnt(0)" ::: "memory");
  __builtin_amdgcn_s_barrier();

  // ---- epilogue: per-wave 64x64 C-tile via private LDS (stride 68),
  //      coalesced 128B bf16x8 row stores.
  bf16* Ws = SA_ + w * 4352;  // 64*68 elems = 8704 B/wave
#pragma unroll
  for (int nt = 0; nt < 4; nt++) {
    const float bv = ga.bias[n0 + wc * 64 + nt * 16 + l15];
#pragma unroll
    for (int mt = 0; mt < 4; mt++)
#pragma unroll
      for (int r = 0; r < 4; r++)
        Ws[(mt * 16 + q * 4 + r) * 68 + nt * 16 + l15] =
            (bf16)(acc[mt][nt][r] + bv);
  }
#pragma unroll
  for (int p = 0; p < 8; p++) {
    const int lr = p * 8 + (lane >> 3), c0 = (lane & 7) * 8;
    bf16x4 lo = *(const bf16x4*)(Ws + lr * 68 + c0);
    bf16x4 hi = *(const bf16x4*)(Ws + lr * 68 + c0 + 4);
    bf16x8 o;
#pragma unroll
    for (int j = 0; j < 4; j++) { o[j] = lo[j]; o[j + 4] = hi[j]; }
    *(bf16x8*)((bf16*)ga.C + (size_t)(m0 + wr * 64 + lr) * N + n0 + wc * 64 + c0) = o;
  }
}

// ---------------------------------------------------------------------------
// Out-projection GEMM: 128x128 tile -> 256 blocks = exactly 1 block/CU.
// Triple-buffer / counted-vmcnt(4) / chunk-XOR as gemm128_k. f32 C via
// LDS-staged epilogue -> 128B-aligned f32x4 line stores.
__global__ __launch_bounds__(512, 1) void gemmo_k(const bf16* __restrict__ A,
                                                  const bf16* __restrict__ Bt,
                                                  const float* __restrict__ bias,
                                                  float* __restrict__ C,
                                                  int M, int N, int K) {
  // 96 KB: A bufs 3x16KB, B bufs 3x16KB. Epilogue reuse: 8 waves x 9216B.
  __shared__ __align__(16) bf16 SA_[49152];
  bf16* const SB_ = SA_ + 24576;

  const int id = blockIdx.x;                 // nwg = 256
  const int wgid = (id & 7) * 32 + (id >> 3);
  const int tx = wgid & 7, ty = wgid >> 3;   // 8 consecutive share A panel
  const int m0 = ty * 128, n0 = tx * 128;

  const int tid = threadIdx.x;
  const int lane = tid & 63, w = tid >> 6;
  const int l15 = lane & 15, q = lane >> 4;
  const int wr = w >> 2, wc = w & 3;     // 2M x 4N

  const bf16* gA[2];
  const bf16* gB[2];
  int dd[2];
#pragma unroll
  for (int i = 0; i < 2; i++) {
    const int ci = i * 512 + w * 64 + lane;
    const int row = ci >> 3, sc = (ci & 7) ^ (row & 7);
    gA[i] = A + (size_t)(m0 + row) * K + sc * 8;
    gB[i] = Bt + (size_t)(n0 + row) * K + sc * 8;
    dd[i] = ci * 8;
  }

  const int cA0 = (q ^ (l15 & 7)) * 8;
  const int cA1 = ((4 + q) ^ (l15 & 7)) * 8;

  f32x4 acc[4][2] = {};
  const int NT = K >> 6;  // 16

#pragma unroll
  for (int tt = 0; tt < 2; tt++) {
    const int k0 = tt * 64;
    gload_lds16(gA[0] + k0, SA_ + tt * 8192 + dd[0]);
    gload_lds16(gA[1] + k0, SA_ + tt * 8192 + dd[1]);
    gload_lds16(gB[0] + k0, SB_ + tt * 8192 + dd[0]);
    gload_lds16(gB[1] + k0, SB_ + tt * 8192 + dd[1]);
  }
  asm volatile("s_waitcnt vmcnt(4)" ::: "memory");
  __builtin_amdgcn_s_barrier();

  for (int t = 0; t < NT; ++t) {
    const int rb = t % 3;
    const int wb = (t + 2) % 3;
    const int kpre = ((t + 2 < NT) ? t + 2 : NT - 1) << 6;
    gload_lds16(gA[0] + kpre, SA_ + wb * 8192 + dd[0]);
    gload_lds16(gA[1] + kpre, SA_ + wb * 8192 + dd[1]);
    gload_lds16(gB[0] + kpre, SB_ + wb * 8192 + dd[0]);
    gload_lds16(gB[1] + kpre, SB_ + wb * 8192 + dd[1]);

    const bf16* Ab = SA_ + rb * 8192;
    const bf16* Bb = SB_ + rb * 8192;
    bf16x8 a[4][2], b[2][2];
#pragma unroll
    for (int mt = 0; mt < 4; mt++) {
      const int ro = (wr * 64 + mt * 16 + l15) * 64;
      a[mt][0] = *(const bf16x8*)(Ab + ro + cA0);
      a[mt][1] = *(const bf16x8*)(Ab + ro + cA1);
    }
#pragma unroll
    for (int nt = 0; nt < 2; nt++) {
      const int ro = (wc * 32 + nt * 16 + l15) * 64;
      b[nt][0] = *(const bf16x8*)(Bb + ro + cA0);
      b[nt][1] = *(const bf16x8*)(Bb + ro + cA1);
    }

    __builtin_amdgcn_s_setprio(1);
#pragma unroll
    for (int mt = 0; mt < 4; mt++)
#pragma unroll
      for (int nt = 0; nt < 2; nt++)
#pragma unroll
        for (int kk = 0; kk < 2; kk++)
          acc[mt][nt] = __builtin_amdgcn_mfma_f32_16x16x32_bf16(
              a[mt][kk], b[nt][kk], acc[mt][nt], 0, 0, 0);
    __builtin_amdgcn_s_setprio(0);

    asm volatile("s_waitcnt vmcnt(4)" ::: "memory");
    __builtin_amdgcn_s_barrier();
  }

  // ---- drain tail prefetches before LDS reuse.
  asm volatile("s_waitcnt vmcnt(0)" ::: "memory");
  __builtin_amdgcn_s_barrier();

  // ---- epilogue: per-wave 64x32 f32 tile via LDS (stride 36 f32),
  //      then 128B f32x4 line stores.
  float* Ws = (float*)SA_ + w * 2304;  // 64*36 f32 = 9216 B/wave
#pragma unroll
  for (int nt = 0; nt < 2; nt++) {
    const float bv = bias[n0 + wc * 32 + nt * 16 + l15];
#pragma unroll
    for (int mt = 0; mt < 4; mt++)
#pragma unroll
      for (int r = 0; r < 4; r++)
        Ws[(mt * 16 + q * 4 + r) * 36 + nt * 16 + l15] = acc[mt][nt][r] + bv;
  }
#pragma unroll
  for (int p = 0; p < 8; p++) {
    const int lr = p * 8 + (lane >> 3), c0 = (lane & 7) * 4;
    f32x4 v = *(const f32x4*)(Ws + lr * 36 + c0);
    *(f32x4*)(C + (size_t)(m0 + wr * 64 + lr) * N + n0 + wc * 32 + c0) = v;
  }
}

// ---------------------------------------------------------------------------
// Causal flash attention (round-7 measured-good). 32x32x16 MFMA, swapped
// QK^T (S^T = K@Q^T), P in registers (cvt_pk_bf16 + permlane32_swap).
// 128-row Q tile per block, 512 threads = 8 waves = (q-quarter qq) x
// (key-half kh). Grid 512 = 2 blocks/CU co-resident (16 waves/CU); paired
// xt = tau<8 ? tau : 23-tau -> uniform 34 iters per CU.
__global__ __launch_bounds__(512, 4) void attn_k(const bf16* __restrict__ Qp,
                                                 const bf16* __restrict__ Kp,
                                                 const bf16* __restrict__ Vp,
                                                 bf16* __restrict__ Op) {
  const int g = blockIdx.x;          // 0..511
  const int xcd = g & 7, s = g >> 3;
  const int gl = s & 3, tau = s >> 2;        // (b,h)-in-XCD, tile slot 0..15
  const int bh = xcd * 4 + gl;
  const int b = bh >> 4, h = bh & 15;
  const int xt = (tau < 8) ? tau : 23 - tau;  // pair {t,t+8}: xt sums to 15
  const int i0 = xt * 128;
  const int NI = 2 * xt + 2;                  // 64-key tiles, >= 2

  const int tid = threadIdx.x;
  const int lane = tid & 63, w = tid >> 6;
  const int l31 = lane & 31, hi = lane >> 5;
  const int qq = w >> 1, kh = w & 1;          // q-quarter, key-half

  // staging 32KB ([2][64][64] x2); epilogue reuse 32KB osum + 1KB aux
  __shared__ __align__(16) char smem[33792];
  bf16 (*Ks)[64][64] = (bf16 (*)[64][64])smem;             // [2][64][64] swz
  bf16 (*Vts)[64][64] = (bf16 (*)[64][64])(smem + 16384);  // [2][64][64] [d][k]

  const size_t headoff = (size_t)b * S_ * DM + h * HD;
  const bf16* Kb = Kp + headoff;
  const bf16* Vb = Vp + headoff;

  // K staging: 512 threads x one bf16x8 = 64x64.
  const int kr = tid >> 3, kcb = (tid & 7) * 8;
  const int cK = ((tid & 7) ^ (kr & 7)) * 8;
  // V staging: 4 keys x 2 d per thread.
  const int d0 = (tid & 31) * 2, kq = (tid >> 5) * 4;
  const int cV0 = ((kq >> 3) ^ (d0 & 7)) * 8 + (kq & 7);
  const int cV1 = ((kq >> 3) ^ ((d0 + 1) & 7)) * 8 + (kq & 7);
  const float QSCALE = 0.04508422f;  // log2(e)/32

  // ---- Q -> registers in B-frag layout (n=q=l31, k=kk*16+hi*8+j), prescaled
  bf16x8 qreg[4];
  {
    const bf16* qb = Qp + headoff + (size_t)(i0 + qq * 32 + l31) * DM + hi * 8;
#pragma unroll
    for (int kk = 0; kk < 4; kk++) {
      bf16x8 v = *(const bf16x8*)(qb + kk * 16);
      bf16x8 o;
#pragma unroll
      for (int j = 0; j < 8; j++) o[j] = (bf16)((float)v[j] * QSCALE);
      qreg[kk] = o;
    }
  }

  // ---- prologue: tile 0 -> buf 0; issue tile 1 into regs (NI >= 2 always)
  bf16x8 kR = *(const bf16x8*)(Kb + (size_t)kr * DM + kcb);
  bf16x2 vR[4];
#pragma unroll
  for (int j = 0; j < 4; j++)
    vR[j] = *(const bf16x2*)(Vb + (size_t)(kq + j) * DM + d0);
  *(bf16x8*)&Ks[0][kr][cK] = kR;
  {
    bf16x4 vlo, vhi;
#pragma unroll
    for (int j = 0; j < 4; j++) { vlo[j] = vR[j][0]; vhi[j] = vR[j][1]; }
    *(bf16x4*)&Vts[0][d0][cV0] = vlo;
    *(bf16x4*)&Vts[0][d0 + 1][cV1] = vhi;
  }
  kR = *(const bf16x8*)(Kb + (size_t)(64 + kr) * DM + kcb);
#pragma unroll
  for (int j = 0; j < 4; j++)
    vR[j] = *(const bf16x2*)(Vb + (size_t)(64 + kq + j) * DM + d0);
  __syncthreads();

  f32x16 oacc0 = {}, oacc1 = {};  // O^T partial: d-tiles 0..31 / 32..63, col q
  float rsum = 0.f;
  int buf = 0;
  const int qbase = i0 + qq * 32;

  for (int t = 0; t < NI; ++t, buf ^= 1) {
    // ---- write tile t+1 (regs loaded at t-1; latency budget = full iter)
    if (t + 1 < NI) {
      *(bf16x8*)&Ks[buf ^ 1][kr][cK] = kR;
      bf16x4 vlo, vhi;
#pragma unroll
      for (int j = 0; j < 4; j++) { vlo[j] = vR[j][0]; vhi[j] = vR[j][1]; }
      *(bf16x4*)&Vts[buf ^ 1][d0][cV0] = vlo;
      *(bf16x4*)&Vts[buf ^ 1][d0 + 1][cV1] = vhi;
    }
    // ---- issue loads for tile t+2
    if (t + 2 < NI) {
      const size_t jn = (size_t)(t + 2) * 64;
      kR = *(const bf16x8*)(Kb + (jn + kr) * DM + kcb);
#pragma unroll
      for (int j = 0; j < 4; j++)
        vR[j] = *(const bf16x2*)(Vb + (jn + kq + j) * DM + d0);
    }

    const int kbase = t * 64 + kh * 32;
    if (kbase <= qbase + 31) {  // not fully masked for this wave
      // ---- S^T = K @ Q^T, 2+2 split accumulator chains
      f32x16 sa = {}, sb = {};
      __builtin_amdgcn_s_setprio(1);
#pragma unroll
      for (int kk = 0; kk < 2; kk++) {
        bf16x8 ka = *(const bf16x8*)
            &Ks[buf][kh * 32 + l31][((2 * kk + hi) ^ (l31 & 7)) * 8];
        sa = __builtin_amdgcn_mfma_f32_32x32x16_bf16(ka, qreg[kk], sa, 0, 0, 0);
      }
#pragma unroll
      for (int kk = 2; kk < 4; kk++) {
        bf16x8 ka = *(const bf16x8*)
            &Ks[buf][kh * 32 + l31][((2 * kk + hi) ^ (l31 & 7)) * 8];
        sb = __builtin_amdgcn_mfma_f32_32x32x16_bf16(ka, qreg[kk], sb, 0, 0, 0);
      }
      __builtin_amdgcn_s_setprio(0);

      // ---- p = exp2(sa+sb). C-layout: col=q=l31, row=key=(r&3)+8*(r>>2)+4*hi
      float p[16];
      if (kbase + 31 > qbase) {  // diagonal-crossing: predicated
        const int qrl = qbase + l31;
#pragma unroll
        for (int r = 0; r < 16; r++) {
          const int keyl = kbase + (r & 3) + 8 * (r >> 2) + 4 * hi;
          p[r] = (keyl <= qrl) ? __builtin_amdgcn_exp2f(sa[r] + sb[r]) : 0.f;
        }
      } else {
#pragma unroll
        for (int r = 0; r < 16; r++)
          p[r] = __builtin_amdgcn_exp2f(sa[r] + sb[r]);
      }
      // tree-reduce rsum
      {
        float q0 = (p[0] + p[1]) + (p[2] + p[3]);
        float q1 = (p[4] + p[5]) + (p[6] + p[7]);
        float q2 = (p[8] + p[9]) + (p[10] + p[11]);
        float q3 = (p[12] + p[13]) + (p[14] + p[15]);
        rsum += (q0 + q1) + (q2 + q3);
      }

      // ---- pack quads to bf16 words
      u32 Aq[4][2];
#pragma unroll
      for (int t2 = 0; t2 < 4; t2++) {
        Aq[t2][0] = cvt_pk_bf16(p[4 * t2 + 0], p[4 * t2 + 1]);
        Aq[t2][1] = cvt_pk_bf16(p[4 * t2 + 2], p[4 * t2 + 3]);
      }
      // ---- exchange to PV B-frag via permlane32_swap
      bf16x8 pb[2];
#pragma unroll
      for (int s2 = 0; s2 < 2; s2++) {
        auto e0 = __builtin_amdgcn_permlane32_swap(Aq[2 * s2][0], Aq[2 * s2 + 1][0], false, false);
        auto e1 = __builtin_amdgcn_permlane32_swap(Aq[2 * s2][1], Aq[2 * s2 + 1][1], false, false);
        union { u32 u[4]; bf16x8 v; } cv;
        cv.u[0] = e0[0]; cv.u[1] = e1[0]; cv.u[2] = e0[1]; cv.u[3] = e1[1];
        pb[s2] = cv.v;
      }

      // ---- O^T += V^T @ P : A = Vts[d][key], B = pb (keys of this kh-half)
      __builtin_amdgcn_s_setprio(1);
#pragma unroll
      for (int s2 = 0; s2 < 2; s2++) {
        const int cv = ((kh * 4 + s2 * 2 + hi) ^ (l31 & 7)) * 8;
        bf16x8 va0 = *(const bf16x8*)&Vts[buf][l31][cv];
        bf16x8 va1 = *(const bf16x8*)&Vts[buf][32 + l31][cv];
        oacc0 = __builtin_amdgcn_mfma_f32_32x32x16_bf16(va0, pb[s2], oacc0, 0, 0, 0);
        oacc1 = __builtin_amdgcn_mfma_f32_32x32x16_bf16(va1, pb[s2], oacc1, 0, 0, 0);
      }
      __builtin_amdgcn_s_setprio(0);
    }

    __syncthreads();  // tile t reads done + tile t+1 writes visible
  }

  // ---- cross-wave (kh) reduction + transposed coalesced output ----
  // osum [qq][slot=8][lane=64][4] f32 (32 KB): kh=0 waves write, kh=1 add.
  float rtot_w = rsum + __shfl_xor(rsum, 32);
  float* osum = (float*)smem;
  float* auxf = (float*)(smem + 32768);   // [w][32] rsum partials
  if (kh == 0) {
#pragma unroll
    for (int m = 0; m < 2; m++)
#pragma unroll
      for (int rq = 0; rq < 4; rq++) {
        f32x4 v4;
#pragma unroll
        for (int e = 0; e < 4; e++)
          v4[e] = m ? oacc1[rq * 4 + e] : oacc0[rq * 4 + e];
        *(f32x4*)(osum + qq * 2048 + (m * 4 + rq) * 256 + lane * 4) = v4;
      }
  }
  if (lane < 32) auxf[w * 32 + lane] = rtot_w;
  __syncthreads();
  if (kh == 1) {
#pragma unroll
    for (int m = 0; m < 2; m++)
#pragma unroll
      for (int rq = 0; rq < 4; rq++) {
        float* pp = osum + qq * 2048 + (m * 4 + rq) * 256 + lane * 4;
        f32x4 v4 = *(f32x4*)pp;
#pragma unroll
        for (int e = 0; e < 4; e++)
          v4[e] += m ? oacc1[rq * 4 + e] : oacc0[rq * 4 + e];
        *(f32x4*)pp = v4;
      }
  }
  __syncthreads();

  {
    const int q = tid >> 2, q31b = q & 31, qq2 = q >> 5;
    const float rtot = auxf[(qq2 * 2 + 0) * 32 + q31b] + auxf[(qq2 * 2 + 1) * 32 + q31b];
    const float rinv = 1.0f / rtot;
    const int dbase = (tid & 3) * 16;
    bf16* orow = Op + headoff + (size_t)(i0 + q) * DM + dbase;
#pragma unroll
    for (int gg = 0; gg < 2; gg++) {
      bf16x8 o8;
#pragma unroll
      for (int e = 0; e < 8; e++) {
        const int d = dbase + gg * 8 + e;
        const int base = (((d >> 5) << 2) | ((d >> 3) & 3)) * 256 +
                         (q31b + 32 * ((d >> 2) & 1)) * 4 + (d & 3);
        o8[e] = (bf16)(osum[qq2 * 2048 + base] * rinv);
      }
      *(bf16x8*)(orow + gg * 8) = o8;
    }
  }
}

// ---------------------------------------------------------------------------
extern "C" void kernel_launch(void* const* d_in, const int* in_sizes, int n_in,
                              void* d_out, int out_size, void* d_ws, size_t ws_size,
                              hipStream_t stream) {
  const float* q_in = (const float*)d_in[0];
  const float* k_in = (const float*)d_in[1];
  const float* v_in = (const float*)d_in[2];
  // d_in[3] = causal mask, implemented analytically
  const float* Wq = (const float*)d_in[4];
  const float* bq = (const float*)d_in[5];
  const float* Wk = (const float*)d_in[6];
  const float* bk = (const float*)d_in[7];
  const float* Wv = (const float*)d_in[8];
  const float* bv = (const float*)d_in[9];
  const float* Wo = (const float*)d_in[10];
  const float* bo = (const float*)d_in[11];

  bf16* ws = (bf16*)d_ws;
  const size_t NQ = (size_t)B_ * S_ * DM;  // 4M elements
  bf16* Qp = ws;                           // attn writes in-place
  bf16* Kp = ws + NQ;
  bf16* Vp = ws + 2 * NQ;
  bf16* WqT = ws + 3 * NQ;                 // bf16 W^T, 1M elems each
  bf16* WkT = WqT + (size_t)DM * DM;
  bf16* WvT = WkT + (size_t)DM * DM;
  bf16* WoT = WvT + (size_t)DM * DM;       // 32 MB total

  transposeW_k<<<dim3(32, 32, 4), dim3(32, 8), 0, stream>>>(
      Wq, Wk, Wv, Wo, WqT, WkT, WvT, WoT);

  // QKV: reads f32 activations directly (convert fused into A-staging)
  GArgs3 g3;
  g3.g[0] = {q_in, WqT, bq, Qp};
  g3.g[1] = {k_in, WkT, bk, Kp};
  g3.g[2] = {v_in, WvT, bv, Vp};
  gemm128_k<<<dim3(384), 512, 0, stream>>>(g3, B_ * S_, DM, DM);

  // 128-row Q tiles: 16 tiles x 32 (b,h) = 512 blocks x 512 threads
  attn_k<<<dim3(512, 1, 1), 512, 0, stream>>>(Qp, Kp, Vp, Qp);

  // out-projection: 128x128 tiles -> 256 blocks = exactly 1 block/CU
  gemmo_k<<<dim3(256), 512, 0, stream>>>(Qp, WoT, bo, (float*)d_out,
                                         B_ * S_, DM, DM);
}